// Round 5
// baseline (1272.985 us; speedup 1.0000x reference)
//
#include <hip/hip_runtime.h>
#include <stdint.h>

#define BB 16
#define NN 2048
#define DD 128
#define CC 8

typedef unsigned long long u64;

#define BITS_BLOCKS (BB * NN / 4)   // 8192 buildbits blocks in fused prep

// ===========================================================================
// K_prep (fused): blocks [0, 8192) = buildbits; blocks [8192, 8208) = sort.
//   buildbits: neighbors f32 [B,N,N] -> bits[b][r] (64 u32 words per row).
//   sort: per-batch (conf desc, idx asc) -> orig/inv/runExt/singleton flags.
// ===========================================================================
__global__ __launch_bounds__(256) void k_prep(const float* __restrict__ nb,
                                              const float* __restrict__ confid,
                                              uint32_t* __restrict__ bits,
                                              uint32_t* __restrict__ orig,
                                              uint32_t* __restrict__ inv,
                                              uint32_t* __restrict__ runExt,
                                              uint32_t* __restrict__ singBits) {
    __shared__ u64 keys[NN];          // 16 KB (sort blocks only)
    __shared__ uint32_t scan[NN];     // 8 KB
    __shared__ uint32_t rstart[NN];   // 8 KB

    if (blockIdx.x < BITS_BLOCKS) {
        // ---------------- buildbits ----------------
        int lane = threadIdx.x & 63;
        int wave = threadIdx.x >> 6;
        int row  = blockIdx.x * 4 + wave;             // [0, BB*NN)
        const float* src = nb + (size_t)row * NN;
        uint64_t* dst = (uint64_t*)bits + (size_t)row * (NN / 64);
        for (int j = 0; j < NN / 64; j++) {
            float v = src[j * 64 + lane];             // coalesced 256B
            uint64_t m = __ballot(v == 1.0f);         // bit l <-> col 64j+l
            if (lane == 0) dst[j] = m;
        }
        return;
    }

    // ---------------- sort ----------------
    int b = blockIdx.x - BITS_BLOCKS, tid = threadIdx.x;
    const float* cb = confid + (size_t)b * NN * CC;

    for (int i = tid; i < NN; i += 256) {
        const float4* p4 = (const float4*)(cb + (size_t)i * CC);
        float4 a = p4[0], c = p4[1];
        float cf = fmaxf(fmaxf(fmaxf(a.x, a.y), fmaxf(a.z, a.w)),
                         fmaxf(fmaxf(c.x, c.y), fmaxf(c.z, c.w)));
        keys[i] = ((u64)__float_as_uint(cf) << 32) | (uint32_t)(NN - 1 - i);
    }
    __syncthreads();

    for (int k = 2; k <= NN; k <<= 1) {
        for (int j = k >> 1; j > 0; j >>= 1) {
            for (int i = tid; i < NN; i += 256) {
                int ixj = i ^ j;
                if (ixj > i) {
                    bool up = ((i & k) == 0);
                    u64 a = keys[i], c = keys[ixj];
                    if ((a < c) == up) { keys[i] = c; keys[ixj] = a; }  // descending
                }
            }
            __syncthreads();
        }
    }

    for (int p = tid; p < NN; p += 256) {
        uint32_t og = (uint32_t)(NN - 1) - (uint32_t)(keys[p] & 0xFFFFFFFFu);
        orig[b * NN + p] = og;
        inv[b * NN + og] = (uint32_t)p;
    }

    // runStart: prefix-max of (tie ? 0 : p)
    __syncthreads();
    for (int p = tid; p < NN; p += 256) {
        bool tie = (p > 0) && ((uint32_t)(keys[p] >> 32) == (uint32_t)(keys[p - 1] >> 32));
        scan[p] = tie ? 0u : (uint32_t)p;
    }
    __syncthreads();
    for (int s = 1; s < NN; s <<= 1) {
        uint32_t v[8];
        for (int p = tid, q = 0; p < NN; p += 256, q++)
            v[q] = (p >= s) ? max(scan[p], scan[p - s]) : scan[p];
        __syncthreads();
        for (int p = tid, q = 0; p < NN; p += 256, q++) scan[p] = v[q];
        __syncthreads();
    }
    for (int p = tid; p < NN; p += 256) rstart[p] = scan[p];

    // runEnd: suffix-min of (tieNext ? BIG : p)
    __syncthreads();
    for (int p = tid; p < NN; p += 256) {
        bool tieN = (p < NN - 1) &&
                    ((uint32_t)(keys[p + 1] >> 32) == (uint32_t)(keys[p] >> 32));
        scan[p] = tieN ? 0x7FFFFFFFu : (uint32_t)p;
    }
    __syncthreads();
    for (int s = 1; s < NN; s <<= 1) {
        uint32_t v[8];
        for (int p = tid, q = 0; p < NN; p += 256, q++)
            v[q] = (p + s < NN) ? min(scan[p], scan[p + s]) : scan[p];
        __syncthreads();
        for (int p = tid, q = 0; p < NN; p += 256, q++) scan[p] = v[q];
        __syncthreads();
    }
    for (int p = tid; p < NN; p += 256)
        runExt[b * NN + p] = (scan[p] << 16) | rstart[p];

    __syncthreads();
    if (tid < 64) {   // pack singleton flags: pos 32*tid+k
        uint32_t sw = 0;
        for (int k = 0; k < 32; k++) {
            int p = tid * 32 + k;
            sw |= (rstart[p] == scan[p]) ? (1u << k) : 0u;
        }
        singBits[b * 64 + tid] = sw;
    }
}

// ===========================================================================
// P3: permute adjacency in BIT domain: rowS[b][p][l] bit k =
//     bits[b][orig[p]] bit orig[32l+k]. One wave per 32 rows, row via LDS.
// ===========================================================================
__global__ __launch_bounds__(256) void k_permbits(const uint32_t* __restrict__ bits,
                                                  const uint32_t* __restrict__ orig,
                                                  uint32_t* __restrict__ rowS) {
    __shared__ uint32_t rowLds[4][64];
    int lane = threadIdx.x & 63, wid = threadIdx.x >> 6;
    int waveG = blockIdx.x * 4 + wid;      // [0, 1024): 64 waves per batch
    int b = waveG >> 6;
    int wInB = waveG & 63;
    const uint32_t* ob = orig + b * NN;

    uint32_t ocol[32];                      // my 32 columns' orig indices
    const uint4* obv = (const uint4*)(ob + lane * 32);
#pragma unroll
    for (int q = 0; q < 8; q++) {
        uint4 v = obv[q];
        ocol[q * 4 + 0] = v.x; ocol[q * 4 + 1] = v.y;
        ocol[q * 4 + 2] = v.z; ocol[q * 4 + 3] = v.w;
    }

    const uint32_t* bitsB = bits + (size_t)b * NN * 64;
    uint32_t* rsB = rowS + (size_t)b * NN * 64;
    for (int r = 0; r < 32; r++) {
        int p = wInB * 32 + r;
        const uint32_t* src = bitsB + (size_t)ob[p] * 64;
        rowLds[wid][lane] = src[lane];      // in-wave DS ordering guarantees RAW
        uint32_t wb = 0;
#pragma unroll
        for (int k = 0; k < 32; k++) {
            uint32_t c = ocol[k];
            wb |= ((rowLds[wid][c >> 5] >> (c & 31)) & 1u) << k;
        }
        rsB[(size_t)p * 64 + lane] = wb;
    }
}

// ===========================================================================
// K2: serial greedy in sorted domain, 2-deep speculative row prefetch.
// Wave 0 = serial loop; waves 1-3 warm this batch's 512KB rowS slice into L2.
// ===========================================================================
__global__ __launch_bounds__(256, 1) void k_greedy2(const uint32_t* __restrict__ rowS,
                                                    const uint32_t* __restrict__ orig,
                                                    const uint32_t* __restrict__ inv,
                                                    const uint32_t* __restrict__ runExt,
                                                    const uint32_t* __restrict__ singBits,
                                                    float* __restrict__ perm_out) {
    int b = blockIdx.x;
    int lane = threadIdx.x & 63;
    int wid  = threadIdx.x >> 6;
    const uint32_t* rS = rowS + (size_t)b * NN * 64;

    if (wid > 0) {
        // ---- L2 warmers: stream 512KB slice, 8 loads in flight, 2 passes ----
        const uint4* src = (const uint4*)rS;           // NN*16 uint4
        uint32_t acc = 0;
        for (int pass = 0; pass < 2; pass++) {
            for (int i = (wid - 1) * 64 + lane; i < NN * 16; i += 192 * 8) {
                uint32_t a0 = 0;
#pragma unroll
                for (int u = 0; u < 8; u++) {
                    int j = i + u * 192;
                    if (j < NN * 16) {
                        uint4 v = src[j];
                        a0 ^= v.x ^ v.y ^ v.z ^ v.w;
                    }
                }
                acc ^= a0;
            }
        }
        asm volatile("" :: "v"(acc));                  // keep loads live
        return;
    }

    __builtin_amdgcn_s_setprio(1);
    const uint32_t* ob = orig + b * NN;
    const uint32_t* ib = inv + b * NN;
    const uint32_t* rE = runExt + b * NN;
    float* po = perm_out + b * NN;

    uint32_t availW = 0xFFFFFFFFu, nbhdW = 0u, unvisW = 0xFFFFFFFFu;
    uint32_t nonSingW = ~singBits[b * 64 + lane];

    int cA = -1, cB = -1;            // predicted next / next-next picks (uniform)
    uint32_t rowA = 0, rowB = 0;     // their prefetched row words (per-lane)

    for (int t = 0; t < NN; t++) {
        uint32_t w = nbhdW & availW;
        u64 m = __ballot(w != 0u);
        int p;
        bool positive;
        if (m) {                                   // fast path
            int L = __ffsll(m) - 1;
            uint32_t wl = (uint32_t)__builtin_amdgcn_readlane((int)w, L);
            p = L * 32 + (__ffs(wl) - 1);
            positive = true;
        } else if (__ballot(nbhdW != 0u)) {        // rare: nbhd nonempty, all zeroed
            uint32_t nw = nbhdW, mo = 0xFFFFFFFFu; // -> min orig index among nbhd
            while (nw) {
                int k = __ffs(nw) - 1; nw &= nw - 1;
                mo = min(mo, ob[lane * 32 + k]);
            }
#pragma unroll
            for (int s = 32; s; s >>= 1)
                mo = min(mo, (uint32_t)__shfl_xor((int)mo, s, 64));
            p = (int)ib[mo];
            positive = false;
        } else {                                   // nbhd empty: global argmax
            u64 ma = __ballot(availW != 0u);
            if (ma) {
                int L = __ffsll(ma) - 1;
                uint32_t wl = (uint32_t)__builtin_amdgcn_readlane((int)availW, L);
                p = L * 32 + (__ffs(wl) - 1);
                positive = true;
            } else {                               // all conf zero -> argmax = idx 0
                p = (int)ib[0];
                positive = false;
            }
        }
        p = __builtin_amdgcn_readfirstlane(p);

        // ---- row for pick p: prediction cache hit (usual) or demand load ----
        uint32_t rowW;
        if (p == cA)      rowW = rowA;
        else if (p == cB) rowW = rowB;
        else              rowW = rS[((size_t)p << 6) + lane];

        uint32_t pbit = (lane == (p >> 5)) ? (1u << (p & 31)) : 0u;
        if (positive) {
            availW &= ~pbit;                          // optimistic singleton clear
            uint32_t nsw = (uint32_t)__builtin_amdgcn_readlane((int)nonSingW, p >> 5);
            if ((nsw >> (p & 31)) & 1u) {             // rare tie-run: clear [rs,re]
                uint32_t ext = rE[p];
                int rs  = (int)(ext & 0xFFFFu);
                int ren = (int)(ext >> 16);
                int lo = rs - lane * 32;      lo = lo < 0 ? 0 : (lo > 32 ? 32 : lo);
                int hi = ren + 1 - lane * 32; hi = hi < 0 ? 0 : (hi > 32 ? 32 : hi);
                if (hi > lo) {
                    uint32_t mh = (hi >= 32) ? 0xFFFFFFFFu : ((1u << hi) - 1u);
                    uint32_t ml = (1u << lo) - 1u;
                    availW &= ~(mh & ~ml);
                }
            }
        }

        // ---- speculative candidates for t+1 / t+2 (independent of rowW) ----
        uint32_t w2 = (w & ~pbit) & availW;
        u64 m2 = __ballot(w2 != 0u);
        int c1 = -1, c2 = -1;
        if (m2) {
            int L1 = __ffsll(m2) - 1;
            uint32_t wl1 = (uint32_t)__builtin_amdgcn_readlane((int)w2, L1);
            int b1 = __ffs(wl1) - 1;
            c1 = L1 * 32 + b1;
            uint32_t wl1r = wl1 & (wl1 - 1);
            if (wl1r) {
                c2 = L1 * 32 + (__ffs(wl1r) - 1);
            } else {
                u64 m2r = m2 & (m2 - 1);
                if (m2r) {
                    int L2 = __ffsll(m2r) - 1;
                    uint32_t wl2 = (uint32_t)__builtin_amdgcn_readlane((int)w2, L2);
                    c2 = L2 * 32 + (__ffs(wl2) - 1);
                }
            }
        }
        // refresh cache; reuse in-flight rows when candidate already cached
        uint32_t nrowA = 0, nrowB = 0;
        if (c1 >= 0) {
            if (c1 == cA)      nrowA = rowA;
            else if (c1 == cB) nrowA = rowB;
            else               nrowA = rS[((size_t)c1 << 6) + lane];
        }
        if (c2 >= 0) {
            if (c2 == cB)      nrowB = rowB;
            else if (c2 == cA) nrowB = rowA;
            else               nrowB = rS[((size_t)c2 << 6) + lane];
        }
        cA = c1; cB = c2; rowA = nrowA; rowB = nrowB;

        uint32_t ogv = ob[p];                         // uniform scalar load
        if (lane == 0) po[t] = (float)ogv;

        // ---- merge (waits on rowW only if demand-loaded/late) ----
        nbhdW = (nbhdW & ~pbit) | (rowW & unvisW);
        unvisW &= ~pbit;
    }
}

// ===========================================================================
// Fallback (ws too small): direct-f32 greedy, contiguous-lane ownership.
// ===========================================================================
__global__ __launch_bounds__(64, 1) void k_greedy_fb(const float* __restrict__ confid,
                                                     const float* __restrict__ nb,
                                                     float* __restrict__ perm_out) {
    int b = blockIdx.x, lane = threadIdx.x;
    float conf[32];
    {
        const float* cb = confid + (size_t)b * NN * CC + (size_t)lane * 32 * CC;
#pragma unroll
        for (int k = 0; k < 32; k++) {
            const float4* p = (const float4*)(cb + k * CC);
            float4 a = p[0], c = p[1];
            conf[k] = fmaxf(fmaxf(fmaxf(a.x, a.y), fmaxf(a.z, a.w)),
                            fmaxf(fmaxf(c.x, c.y), fmaxf(c.z, c.w)));
        }
    }
    uint32_t nbhd = 0u, unvis = 0xFFFFFFFFu;
    const float* nbb = nb + (size_t)b * NN * NN;
    float* po = perm_out + (size_t)b * NN;
    for (int t = 0; t < NN; t++) {
        float bv = -1.0f; int bk = 0;
#pragma unroll
        for (int k = 0; k < 32; k++) {
            float v = ((nbhd >> k) & 1u) ? conf[k] : -1.0f;
            bool g = v > bv; bv = g ? v : bv; bk = g ? k : bk;
        }
        u64 pk = 0ULL;
        if (bv >= 0.0f)
            pk = ((u64)__float_as_uint(bv) << 32) | (unsigned)(NN - (lane * 32 + bk));
#pragma unroll
        for (int mm = 32; mm; mm >>= 1) {
            u64 o = __shfl_xor(pk, mm, 64);
            pk = (o > pk) ? o : pk;
        }
        if (pk == 0ULL) {
            float av = conf[0]; int ak = 0;
#pragma unroll
            for (int k = 1; k < 32; k++) {
                bool g = conf[k] > av; av = g ? conf[k] : av; ak = g ? k : ak;
            }
            u64 pa = ((u64)__float_as_uint(av) << 32) | (unsigned)(NN - (lane * 32 + ak));
#pragma unroll
            for (int mm = 32; mm; mm >>= 1) {
                u64 o = __shfl_xor(pa, mm, 64);
                pa = (o > pa) ? o : pa;
            }
            pk = pa;
        }
        int fc = NN - (int)(unsigned)(pk & 0xFFFFFFFFull);
        float cfc = __uint_as_float((unsigned)(pk >> 32));
        const float4* rp = (const float4*)(nbb + (size_t)fc * NN + lane * 32);
        uint32_t row = 0u;
#pragma unroll
        for (int j = 0; j < 8; j++) {
            float4 f = rp[j];
            row |= (f.x == 1.0f ? 1u : 0u) << (4 * j);
            row |= (f.y == 1.0f ? 1u : 0u) << (4 * j + 1);
            row |= (f.z == 1.0f ? 1u : 0u) << (4 * j + 2);
            row |= (f.w == 1.0f ? 1u : 0u) << (4 * j + 3);
        }
        if (lane == 0) po[t] = (float)fc;
        uint32_t mybit = (lane == (fc >> 5)) ? (1u << (fc & 31)) : 0u;
#pragma unroll
        for (int k = 0; k < 32; k++) conf[k] = (conf[k] == cfc) ? 0.0f : conf[k];
        nbhd = (nbhd & ~mybit) | (row & unvis);
        unvis &= ~mybit;
    }
}

// ===========================================================================
// K3: out0[b,t,:] = vertices[b, perm[t], :]
// ===========================================================================
__global__ __launch_bounds__(256) void k_gather(const float* __restrict__ vtx,
                                                const float* __restrict__ perm_f,
                                                float* __restrict__ out0) {
    int tid = blockIdx.x * 256 + threadIdx.x;
    int d = tid & (DD - 1);
    int t = (tid >> 7) & (NN - 1);
    int b = tid >> 18;
    int p = (int)perm_f[b * NN + t];
    out0[tid] = vtx[(((size_t)b * NN + p) << 7) + d];
}

// ===========================================================================
extern "C" void kernel_launch(void* const* d_in, const int* in_sizes, int n_in,
                              void* d_out, int out_size, void* d_ws, size_t ws_size,
                              hipStream_t stream) {
    const float* vertices   = (const float*)d_in[0];
    const float* confidence = (const float*)d_in[1];
    const float* neighbors  = (const float*)d_in[2];

    float* out0     = (float*)d_out;                   // [B,N,D]
    float* perm_out = out0 + (size_t)BB * NN * DD;     // [B,N] as f32 values

    const size_t rowS_bytes = (size_t)BB * NN * (NN / 8);   // 8 MB
    if (ws_size >= rowS_bytes) {
        uint32_t* rowS = (uint32_t*)d_ws;
        // temps live in the out0 region (fully overwritten by k_gather later):
        // bits 8MB | orig 128KB | inv 128KB | runExt 128KB | singBits 4KB  << 16MB
        uint32_t* bits     = (uint32_t*)out0;
        uint32_t* orig     = bits + (size_t)BB * NN * 64;
        uint32_t* inv      = orig + BB * NN;
        uint32_t* runExt   = inv + BB * NN;
        uint32_t* singBits = runExt + BB * NN;

        k_prep<<<BITS_BLOCKS + BB, 256, 0, stream>>>(neighbors, confidence, bits,
                                                     orig, inv, runExt, singBits);
        k_permbits<<<BB * NN / 128, 256, 0, stream>>>(bits, orig, rowS);
        k_greedy2<<<BB, 256, 0, stream>>>(rowS, orig, inv, runExt, singBits, perm_out);
    } else {
        k_greedy_fb<<<BB, 64, 0, stream>>>(confidence, neighbors, perm_out);
    }
    k_gather<<<(BB * NN * DD) / 256, 256, 0, stream>>>(vertices, perm_out, out0);
}

// Round 6
// 106.681 us; speedup vs baseline: 11.9326x; 11.9326x over previous
//
#include <hip/hip_runtime.h>
#include <stdint.h>

#define BB 16
#define NN 2048
#define DD 128
#define CC 8

typedef unsigned long long u64;

// ===========================================================================
// k_sort: per-batch sort by (conf desc, idx asc). Outputs per batch:
//   orig[p]  : sorted pos -> orig idx
//   inv[i]   : orig idx  -> sorted pos
//   runExt[p]: (runEnd<<16)|runStart of equal-conf run containing p
//   singBits : bit k of word l = run at pos 32l+k is a singleton
//   rsBits   : bit k of word l = pos 32l+k is a run START
// ===========================================================================
__global__ __launch_bounds__(256) void k_sort(const float* __restrict__ confid,
                                              uint32_t* __restrict__ orig,
                                              uint32_t* __restrict__ inv,
                                              uint32_t* __restrict__ runExt,
                                              uint32_t* __restrict__ singBits,
                                              uint32_t* __restrict__ rsBits) {
    __shared__ u64 keys[NN];          // 16 KB
    __shared__ uint32_t scan[NN];     // 8 KB
    __shared__ uint32_t rstart[NN];   // 8 KB
    int b = blockIdx.x, tid = threadIdx.x;
    const float* cb = confid + (size_t)b * NN * CC;

    for (int i = tid; i < NN; i += 256) {
        const float4* p4 = (const float4*)(cb + (size_t)i * CC);
        float4 a = p4[0], c = p4[1];
        float cf = fmaxf(fmaxf(fmaxf(a.x, a.y), fmaxf(a.z, a.w)),
                         fmaxf(fmaxf(c.x, c.y), fmaxf(c.z, c.w)));
        keys[i] = ((u64)__float_as_uint(cf) << 32) | (uint32_t)(NN - 1 - i);
    }
    __syncthreads();

    for (int k = 2; k <= NN; k <<= 1) {
        for (int j = k >> 1; j > 0; j >>= 1) {
            for (int i = tid; i < NN; i += 256) {
                int ixj = i ^ j;
                if (ixj > i) {
                    bool up = ((i & k) == 0);
                    u64 a = keys[i], c = keys[ixj];
                    if ((a < c) == up) { keys[i] = c; keys[ixj] = a; }  // descending
                }
            }
            __syncthreads();
        }
    }

    for (int p = tid; p < NN; p += 256) {
        uint32_t og = (uint32_t)(NN - 1) - (uint32_t)(keys[p] & 0xFFFFFFFFu);
        orig[b * NN + p] = og;
        inv[b * NN + og] = (uint32_t)p;
    }

    // runStart: prefix-max of (tie ? 0 : p)
    __syncthreads();
    for (int p = tid; p < NN; p += 256) {
        bool tie = (p > 0) && ((uint32_t)(keys[p] >> 32) == (uint32_t)(keys[p - 1] >> 32));
        scan[p] = tie ? 0u : (uint32_t)p;
    }
    __syncthreads();
    for (int s = 1; s < NN; s <<= 1) {
        uint32_t v[8];
        for (int p = tid, q = 0; p < NN; p += 256, q++)
            v[q] = (p >= s) ? max(scan[p], scan[p - s]) : scan[p];
        __syncthreads();
        for (int p = tid, q = 0; p < NN; p += 256, q++) scan[p] = v[q];
        __syncthreads();
    }
    for (int p = tid; p < NN; p += 256) rstart[p] = scan[p];

    // runEnd: suffix-min of (tieNext ? BIG : p)
    __syncthreads();
    for (int p = tid; p < NN; p += 256) {
        bool tieN = (p < NN - 1) &&
                    ((uint32_t)(keys[p + 1] >> 32) == (uint32_t)(keys[p] >> 32));
        scan[p] = tieN ? 0x7FFFFFFFu : (uint32_t)p;
    }
    __syncthreads();
    for (int s = 1; s < NN; s <<= 1) {
        uint32_t v[8];
        for (int p = tid, q = 0; p < NN; p += 256, q++)
            v[q] = (p + s < NN) ? min(scan[p], scan[p + s]) : scan[p];
        __syncthreads();
        for (int p = tid, q = 0; p < NN; p += 256, q++) scan[p] = v[q];
        __syncthreads();
    }
    for (int p = tid; p < NN; p += 256)
        runExt[b * NN + p] = (scan[p] << 16) | rstart[p];

    __syncthreads();
    if (tid < 64) {
        uint32_t sw = 0, rw = 0;
        for (int k = 0; k < 32; k++) {
            int p = tid * 32 + k;
            bool isStart = (rstart[p] == (uint32_t)p);
            rw |= isStart ? (1u << k) : 0u;
            sw |= (isStart && scan[p] == (uint32_t)p) ? (1u << k) : 0u;
        }
        singBits[b * 64 + tid] = sw;
        rsBits[b * 64 + tid] = rw;
    }
}

// ===========================================================================
// k_greedy5: one wave per batch.
// Phase 1 (until notNbhd==0, ~20 steps): full greedy; row read directly from
//   f32 neighbors, permuted via register ocol[] (static indices).
// Phase 2: nbhd==unvis forever -> closed form. Fast picks = live & runStart,
//   emitted in parallel (prefix scan); leftovers by ascending orig index.
// ===========================================================================
__global__ __launch_bounds__(64, 1) void k_greedy5(const float* __restrict__ nb,
                                                   const uint32_t* __restrict__ orig,
                                                   const uint32_t* __restrict__ inv,
                                                   const uint32_t* __restrict__ runExt,
                                                   const uint32_t* __restrict__ singBits,
                                                   const uint32_t* __restrict__ rsBits,
                                                   float* __restrict__ perm_out) {
    int b = blockIdx.x, lane = threadIdx.x;
    const uint32_t* ob = orig + b * NN;
    const uint32_t* ib = inv + b * NN;
    const uint32_t* rE = runExt + b * NN;
    const float* nbB = nb + (size_t)b * NN * NN;
    float* po = perm_out + b * NN;

    // my 32 sorted positions' orig indices, in registers (static access only)
    uint32_t ocol[32];
    {
        const uint4* obv = (const uint4*)(ob + lane * 32);
#pragma unroll
        for (int q = 0; q < 8; q++) {
            uint4 v = obv[q];
            ocol[q * 4 + 0] = v.x; ocol[q * 4 + 1] = v.y;
            ocol[q * 4 + 2] = v.z; ocol[q * 4 + 3] = v.w;
        }
    }

    uint32_t availW = 0xFFFFFFFFu, nbhdW = 0u, unvisW = 0xFFFFFFFFu;
    uint32_t nonSingW = ~singBits[b * 64 + lane];

    int t = 0;
    // ------------------------- phase 1 -------------------------
    for (; t < NN; t++) {
        uint32_t w = nbhdW & availW;
        u64 m = __ballot(w != 0u);
        int p;
        bool positive;
        if (m) {
            int L = __ffsll(m) - 1;
            uint32_t wl = (uint32_t)__builtin_amdgcn_readlane((int)w, L);
            p = L * 32 + (__ffs(wl) - 1);
            positive = true;
        } else if (__ballot(nbhdW != 0u)) {        // rare: nbhd nonempty, all zeroed
            uint32_t mo = 0xFFFFFFFFu;
#pragma unroll
            for (int k = 0; k < 32; k++)
                if (nbhdW & (1u << k)) mo = min(mo, ocol[k]);
#pragma unroll
            for (int s = 32; s; s >>= 1)
                mo = min(mo, (uint32_t)__shfl_xor((int)mo, s, 64));
            p = (int)ib[mo];
            positive = false;
        } else {                                   // nbhd empty: global argmax
            u64 ma = __ballot(availW != 0u);
            if (ma) {
                int L = __ffsll(ma) - 1;
                uint32_t wl = (uint32_t)__builtin_amdgcn_readlane((int)availW, L);
                p = L * 32 + (__ffs(wl) - 1);
                positive = true;
            } else {                               // all conf zero -> orig idx 0
                p = (int)ib[0];
                positive = false;
            }
        }
        p = __builtin_amdgcn_readfirstlane(p);

        uint32_t ogv = ob[p];                      // uniform scalar load
        // row for orig node ogv, permuted into sorted domain (static ocol idx)
        const float* rowp = nbB + (size_t)ogv * NN;
        uint32_t row = 0u;
#pragma unroll
        for (int k = 0; k < 32; k++)
            row |= (rowp[ocol[k]] == 1.0f ? 1u : 0u) << k;

        if (lane == 0) po[t] = (float)ogv;

        uint32_t pbit = (lane == (p >> 5)) ? (1u << (p & 31)) : 0u;
        if (positive) {
            availW &= ~pbit;                       // optimistic singleton clear
            uint32_t nsw = (uint32_t)__builtin_amdgcn_readlane((int)nonSingW, p >> 5);
            if ((nsw >> (p & 31)) & 1u) {          // rare tie-run: clear [rs,re]
                uint32_t ext = rE[p];
                int rs  = (int)(ext & 0xFFFFu);
                int ren = (int)(ext >> 16);
                int lo = rs - lane * 32;      lo = lo < 0 ? 0 : (lo > 32 ? 32 : lo);
                int hi = ren + 1 - lane * 32; hi = hi < 0 ? 0 : (hi > 32 ? 32 : hi);
                if (hi > lo) {
                    uint32_t mh = (hi >= 32) ? 0xFFFFFFFFu : ((1u << hi) - 1u);
                    uint32_t ml = (1u << lo) - 1u;
                    availW &= ~(mh & ~ml);
                }
            }
        }
        nbhdW  = (nbhdW & ~pbit) | (row & unvisW);
        unvisW &= ~pbit;

        uint32_t nnb = unvisW & ~nbhdW;            // unreached & unvisited
        if (__ballot(nnb != 0u) == 0ULL) { t++; break; }  // nbhd==unvis forever
    }

    // ------------------------- phase 2 -------------------------
    if (t < NN) {
        uint32_t liveW = availW & unvisW;
        uint32_t rsW = rsBits[b * 64 + lane];
        uint32_t pm = liveW & rsW;                 // fast-pick set (run reps)
        int cnt = __popc(pm);
        int inc = cnt;
#pragma unroll
        for (int s = 1; s < 64; s <<= 1) {
            int o = __shfl_up(inc, s, 64);
            if (lane >= s) inc += o;
        }
        int pre = inc - cnt;                       // exclusive prefix
        int T2 = __shfl(inc, 63, 64);              // total fast picks

        int tt = t + pre;
#pragma unroll
        for (int k = 0; k < 32; k++) {             // static idx -> ocol in regs
            if (pm & (1u << k)) { po[tt] = (float)ocol[k]; tt++; }
        }
        t += T2;

        // leftovers: unvisited non-reps (zero-conf tie losers), ascending orig
        uint32_t lm = unvisW & ~pm;
        while (__ballot(lm != 0u)) {
            uint32_t mo = 0xFFFFFFFFu;
#pragma unroll
            for (int k = 0; k < 32; k++)
                if (lm & (1u << k)) mo = min(mo, ocol[k]);
#pragma unroll
            for (int s = 32; s; s >>= 1)
                mo = min(mo, (uint32_t)__shfl_xor((int)mo, s, 64));
            if (lane == 0) po[t] = (float)mo;
            t++;
#pragma unroll
            for (int k = 0; k < 32; k++)
                if ((lm & (1u << k)) && ocol[k] == mo) lm &= ~(1u << k);
        }
    }
}

// ===========================================================================
// Fallback (ws too small): direct-f32 greedy, contiguous-lane ownership.
// ===========================================================================
__global__ __launch_bounds__(64, 1) void k_greedy_fb(const float* __restrict__ confid,
                                                     const float* __restrict__ nb,
                                                     float* __restrict__ perm_out) {
    int b = blockIdx.x, lane = threadIdx.x;
    float conf[32];
    {
        const float* cb = confid + (size_t)b * NN * CC + (size_t)lane * 32 * CC;
#pragma unroll
        for (int k = 0; k < 32; k++) {
            const float4* p = (const float4*)(cb + k * CC);
            float4 a = p[0], c = p[1];
            conf[k] = fmaxf(fmaxf(fmaxf(a.x, a.y), fmaxf(a.z, a.w)),
                            fmaxf(fmaxf(c.x, c.y), fmaxf(c.z, c.w)));
        }
    }
    uint32_t nbhd = 0u, unvis = 0xFFFFFFFFu;
    const float* nbb = nb + (size_t)b * NN * NN;
    float* po = perm_out + (size_t)b * NN;
    for (int t = 0; t < NN; t++) {
        float bv = -1.0f; int bk = 0;
#pragma unroll
        for (int k = 0; k < 32; k++) {
            float v = ((nbhd >> k) & 1u) ? conf[k] : -1.0f;
            bool g = v > bv; bv = g ? v : bv; bk = g ? k : bk;
        }
        u64 pk = 0ULL;
        if (bv >= 0.0f)
            pk = ((u64)__float_as_uint(bv) << 32) | (unsigned)(NN - (lane * 32 + bk));
#pragma unroll
        for (int mm = 32; mm; mm >>= 1) {
            u64 o = __shfl_xor(pk, mm, 64);
            pk = (o > pk) ? o : pk;
        }
        if (pk == 0ULL) {
            float av = conf[0]; int ak = 0;
#pragma unroll
            for (int k = 1; k < 32; k++) {
                bool g = conf[k] > av; av = g ? conf[k] : av; ak = g ? k : ak;
            }
            u64 pa = ((u64)__float_as_uint(av) << 32) | (unsigned)(NN - (lane * 32 + ak));
#pragma unroll
            for (int mm = 32; mm; mm >>= 1) {
                u64 o = __shfl_xor(pa, mm, 64);
                pa = (o > pa) ? o : pa;
            }
            pk = pa;
        }
        int fc = NN - (int)(unsigned)(pk & 0xFFFFFFFFull);
        float cfc = __uint_as_float((unsigned)(pk >> 32));
        const float4* rp = (const float4*)(nbb + (size_t)fc * NN + lane * 32);
        uint32_t row = 0u;
#pragma unroll
        for (int j = 0; j < 8; j++) {
            float4 f = rp[j];
            row |= (f.x == 1.0f ? 1u : 0u) << (4 * j);
            row |= (f.y == 1.0f ? 1u : 0u) << (4 * j + 1);
            row |= (f.z == 1.0f ? 1u : 0u) << (4 * j + 2);
            row |= (f.w == 1.0f ? 1u : 0u) << (4 * j + 3);
        }
        if (lane == 0) po[t] = (float)fc;
        uint32_t mybit = (lane == (fc >> 5)) ? (1u << (fc & 31)) : 0u;
#pragma unroll
        for (int k = 0; k < 32; k++) conf[k] = (conf[k] == cfc) ? 0.0f : conf[k];
        nbhd = (nbhd & ~mybit) | (row & unvis);
        unvis &= ~mybit;
    }
}

// ===========================================================================
// k_gather: out0[b,t,:] = vertices[b, perm[t], :]
// ===========================================================================
__global__ __launch_bounds__(256) void k_gather(const float* __restrict__ vtx,
                                                const float* __restrict__ perm_f,
                                                float* __restrict__ out0) {
    int tid = blockIdx.x * 256 + threadIdx.x;
    int d = tid & (DD - 1);
    int t = (tid >> 7) & (NN - 1);
    int b = tid >> 18;
    int p = (int)perm_f[b * NN + t];
    out0[tid] = vtx[(((size_t)b * NN + p) << 7) + d];
}

// ===========================================================================
extern "C" void kernel_launch(void* const* d_in, const int* in_sizes, int n_in,
                              void* d_out, int out_size, void* d_ws, size_t ws_size,
                              hipStream_t stream) {
    const float* vertices   = (const float*)d_in[0];
    const float* confidence = (const float*)d_in[1];
    const float* neighbors  = (const float*)d_in[2];

    float* out0     = (float*)d_out;                   // [B,N,D]
    float* perm_out = out0 + (size_t)BB * NN * DD;     // [B,N] as f32 values

    // ws tables: orig | inv | runExt | singBits | rsBits
    const size_t tab_bytes = ((size_t)BB * NN * 3 + (size_t)BB * 64 * 2) * 4;
    if (ws_size >= tab_bytes) {
        uint32_t* orig     = (uint32_t*)d_ws;
        uint32_t* inv      = orig + BB * NN;
        uint32_t* runExt   = inv + BB * NN;
        uint32_t* singBits = runExt + BB * NN;
        uint32_t* rsBits   = singBits + BB * 64;

        k_sort<<<BB, 256, 0, stream>>>(confidence, orig, inv, runExt, singBits, rsBits);
        k_greedy5<<<BB, 64, 0, stream>>>(neighbors, orig, inv, runExt, singBits,
                                         rsBits, perm_out);
    } else {
        k_greedy_fb<<<BB, 64, 0, stream>>>(confidence, neighbors, perm_out);
    }
    k_gather<<<(BB * NN * DD) / 256, 256, 0, stream>>>(vertices, perm_out, out0);
}

// Round 7
// 103.776 us; speedup vs baseline: 12.2666x; 1.0280x over previous
//
#include <hip/hip_runtime.h>
#include <stdint.h>

#define BB 16
#define NN 2048
#define DD 128
#define CC 8

typedef unsigned long long u64;

// ===========================================================================
// k_fused: one block (256 thr) per batch.
//   Stage A (all 4 waves): bitonic sort of (conf desc, idx asc) keys in LDS;
//     derive orig/inv/runExt/singleton/runstart tables -> LDS.
//   Stage B (wave 0 only; waves 1-3 exit): serial greedy.
//     Phase 1 (until unvis==nbhd, ~15 steps): row demand-read from f32
//       neighbors, permuted via register ocol[] (static idx).
//     Phase 2: closed form — fast picks = live run-starts via prefix scan;
//       leftovers ascending orig.
// ===========================================================================
__global__ __launch_bounds__(256, 1) void k_fused(const float* __restrict__ confid,
                                                  const float* __restrict__ nb,
                                                  float* __restrict__ perm_out) {
    __shared__ u64 keys[NN];              // 16 KB
    __shared__ uint32_t scan[NN];         // 8 KB
    __shared__ uint32_t rstart[NN];       // 8 KB
    __shared__ uint32_t sOrig[NN];        // 8 KB
    __shared__ uint32_t sInv[NN];         // 8 KB
    __shared__ uint32_t sRunExt[NN];      // 8 KB
    __shared__ uint32_t sSing[64];        // 256 B
    __shared__ uint32_t sRs[64];          // 256 B

    int b = blockIdx.x, tid = threadIdx.x;
    const float* cb = confid + (size_t)b * NN * CC;

    // ---- keys = (conf_bits << 32) | (NN-1-i)  (desc conf, asc idx) ----
    for (int i = tid; i < NN; i += 256) {
        const float4* p4 = (const float4*)(cb + (size_t)i * CC);
        float4 a = p4[0], c = p4[1];
        float cf = fmaxf(fmaxf(fmaxf(a.x, a.y), fmaxf(a.z, a.w)),
                         fmaxf(fmaxf(c.x, c.y), fmaxf(c.z, c.w)));
        keys[i] = ((u64)__float_as_uint(cf) << 32) | (uint32_t)(NN - 1 - i);
    }
    __syncthreads();

    // ---- bitonic sort, descending ----
    for (int k = 2; k <= NN; k <<= 1) {
        for (int j = k >> 1; j > 0; j >>= 1) {
            for (int i = tid; i < NN; i += 256) {
                int ixj = i ^ j;
                if (ixj > i) {
                    bool up = ((i & k) == 0);
                    u64 a = keys[i], c = keys[ixj];
                    if ((a < c) == up) { keys[i] = c; keys[ixj] = a; }
                }
            }
            __syncthreads();
        }
    }

    for (int p = tid; p < NN; p += 256) {
        uint32_t og = (uint32_t)(NN - 1) - (uint32_t)(keys[p] & 0xFFFFFFFFu);
        sOrig[p] = og;
        sInv[og] = (uint32_t)p;
    }

    // ---- runStart: prefix-max of (tie ? 0 : p) ----
    __syncthreads();
    for (int p = tid; p < NN; p += 256) {
        bool tie = (p > 0) && ((uint32_t)(keys[p] >> 32) == (uint32_t)(keys[p - 1] >> 32));
        scan[p] = tie ? 0u : (uint32_t)p;
    }
    __syncthreads();
    for (int s = 1; s < NN; s <<= 1) {
        uint32_t v[8];
        for (int p = tid, q = 0; p < NN; p += 256, q++)
            v[q] = (p >= s) ? max(scan[p], scan[p - s]) : scan[p];
        __syncthreads();
        for (int p = tid, q = 0; p < NN; p += 256, q++) scan[p] = v[q];
        __syncthreads();
    }
    for (int p = tid; p < NN; p += 256) rstart[p] = scan[p];

    // ---- runEnd: suffix-min of (tieNext ? BIG : p) ----
    __syncthreads();
    for (int p = tid; p < NN; p += 256) {
        bool tieN = (p < NN - 1) &&
                    ((uint32_t)(keys[p + 1] >> 32) == (uint32_t)(keys[p] >> 32));
        scan[p] = tieN ? 0x7FFFFFFFu : (uint32_t)p;
    }
    __syncthreads();
    for (int s = 1; s < NN; s <<= 1) {
        uint32_t v[8];
        for (int p = tid, q = 0; p < NN; p += 256, q++)
            v[q] = (p + s < NN) ? min(scan[p], scan[p + s]) : scan[p];
        __syncthreads();
        for (int p = tid, q = 0; p < NN; p += 256, q++) scan[p] = v[q];
        __syncthreads();
    }
    for (int p = tid; p < NN; p += 256)
        sRunExt[p] = (scan[p] << 16) | rstart[p];

    __syncthreads();
    if (tid < 64) {
        uint32_t sw = 0, rw = 0;
        for (int k = 0; k < 32; k++) {
            int p = tid * 32 + k;
            bool isStart = (rstart[p] == (uint32_t)p);
            rw |= isStart ? (1u << k) : 0u;
            sw |= (isStart && scan[p] == (uint32_t)p) ? (1u << k) : 0u;
        }
        sSing[tid] = sw;
        sRs[tid] = rw;
    }
    __syncthreads();

    // ================= Stage B: wave 0 only =================
    if (tid >= 64) return;
    int lane = tid;

    const float* nbB = nb + (size_t)b * NN * NN;
    float* po = perm_out + b * NN;

    // my 32 sorted positions' orig indices in registers (LDS -> regs, static)
    uint32_t ocol[32];
#pragma unroll
    for (int k = 0; k < 32; k++) ocol[k] = sOrig[lane * 32 + k];

    uint32_t availW = 0xFFFFFFFFu, nbhdW = 0u, unvisW = 0xFFFFFFFFu;
    uint32_t nonSingW = ~sSing[lane];

    int t = 0;
    // ------------------------- phase 1 -------------------------
    for (; t < NN; t++) {
        uint32_t w = nbhdW & availW;
        u64 m = __ballot(w != 0u);
        int p;
        bool positive;
        if (m) {
            int L = __ffsll(m) - 1;
            uint32_t wl = (uint32_t)__builtin_amdgcn_readlane((int)w, L);
            p = L * 32 + (__ffs(wl) - 1);
            positive = true;
        } else if (__ballot(nbhdW != 0u)) {        // rare: nbhd nonempty, all zeroed
            uint32_t mo = 0xFFFFFFFFu;
#pragma unroll
            for (int k = 0; k < 32; k++)
                if (nbhdW & (1u << k)) mo = min(mo, ocol[k]);
#pragma unroll
            for (int s = 32; s; s >>= 1)
                mo = min(mo, (uint32_t)__shfl_xor((int)mo, s, 64));
            p = (int)sInv[mo];
            positive = false;
        } else {                                   // nbhd empty: global argmax
            u64 ma = __ballot(availW != 0u);
            if (ma) {
                int L = __ffsll(ma) - 1;
                uint32_t wl = (uint32_t)__builtin_amdgcn_readlane((int)availW, L);
                p = L * 32 + (__ffs(wl) - 1);
                positive = true;
            } else {                               // all conf zero -> orig idx 0
                p = (int)sInv[0];
                positive = false;
            }
        }
        p = __builtin_amdgcn_readfirstlane(p);

        uint32_t ogv = sOrig[p];                   // LDS broadcast
        const float* rowp = nbB + (size_t)ogv * NN;
        uint32_t row = 0u;
#pragma unroll
        for (int k = 0; k < 32; k++)
            row |= (rowp[ocol[k]] == 1.0f ? 1u : 0u) << k;

        if (lane == 0) po[t] = (float)ogv;

        uint32_t pbit = (lane == (p >> 5)) ? (1u << (p & 31)) : 0u;
        if (positive) {
            availW &= ~pbit;                       // optimistic singleton clear
            uint32_t nsw = (uint32_t)__builtin_amdgcn_readlane((int)nonSingW, p >> 5);
            if ((nsw >> (p & 31)) & 1u) {          // rare tie-run: clear [rs,re]
                uint32_t ext = sRunExt[p];
                int rs  = (int)(ext & 0xFFFFu);
                int ren = (int)(ext >> 16);
                int lo = rs - lane * 32;      lo = lo < 0 ? 0 : (lo > 32 ? 32 : lo);
                int hi = ren + 1 - lane * 32; hi = hi < 0 ? 0 : (hi > 32 ? 32 : hi);
                if (hi > lo) {
                    uint32_t mh = (hi >= 32) ? 0xFFFFFFFFu : ((1u << hi) - 1u);
                    uint32_t ml = (1u << lo) - 1u;
                    availW &= ~(mh & ~ml);
                }
            }
        }
        nbhdW  = (nbhdW & ~pbit) | (row & unvisW);
        unvisW &= ~pbit;

        uint32_t nnb = unvisW & ~nbhdW;            // unreached & unvisited
        if (__ballot(nnb != 0u) == 0ULL) { t++; break; }  // nbhd==unvis forever
    }

    // ------------------------- phase 2 -------------------------
    if (t < NN) {
        uint32_t liveW = availW & unvisW;
        uint32_t rsW = sRs[lane];
        uint32_t pm = liveW & rsW;                 // fast-pick set (run reps)
        int cnt = __popc(pm);
        int inc = cnt;
#pragma unroll
        for (int s = 1; s < 64; s <<= 1) {
            int o = __shfl_up(inc, s, 64);
            if (lane >= s) inc += o;
        }
        int pre = inc - cnt;                       // exclusive prefix
        int T2 = __shfl(inc, 63, 64);              // total fast picks

        int tt = t + pre;
#pragma unroll
        for (int k = 0; k < 32; k++) {
            if (pm & (1u << k)) { po[tt] = (float)ocol[k]; tt++; }
        }
        t += T2;

        // leftovers: unvisited non-reps (zero-conf tie losers), ascending orig
        uint32_t lm = unvisW & ~pm;
        while (__ballot(lm != 0u)) {
            uint32_t mo = 0xFFFFFFFFu;
#pragma unroll
            for (int k = 0; k < 32; k++)
                if (lm & (1u << k)) mo = min(mo, ocol[k]);
#pragma unroll
            for (int s = 32; s; s >>= 1)
                mo = min(mo, (uint32_t)__shfl_xor((int)mo, s, 64));
            if (lane == 0) po[t] = (float)mo;
            t++;
#pragma unroll
            for (int k = 0; k < 32; k++)
                if ((lm & (1u << k)) && ocol[k] == mo) lm &= ~(1u << k);
        }
    }
}

// ===========================================================================
// k_gather: out0[b,t,:] = vertices[b, perm[t], :]
// ===========================================================================
__global__ __launch_bounds__(256) void k_gather(const float* __restrict__ vtx,
                                                const float* __restrict__ perm_f,
                                                float* __restrict__ out0) {
    int tid = blockIdx.x * 256 + threadIdx.x;
    int d = tid & (DD - 1);
    int t = (tid >> 7) & (NN - 1);
    int b = tid >> 18;
    int p = (int)perm_f[b * NN + t];
    out0[tid] = vtx[(((size_t)b * NN + p) << 7) + d];
}

// ===========================================================================
extern "C" void kernel_launch(void* const* d_in, const int* in_sizes, int n_in,
                              void* d_out, int out_size, void* d_ws, size_t ws_size,
                              hipStream_t stream) {
    const float* vertices   = (const float*)d_in[0];
    const float* confidence = (const float*)d_in[1];
    const float* neighbors  = (const float*)d_in[2];

    float* out0     = (float*)d_out;                   // [B,N,D]
    float* perm_out = out0 + (size_t)BB * NN * DD;     // [B,N] as f32 values

    k_fused<<<BB, 256, 0, stream>>>(confidence, neighbors, perm_out);
    k_gather<<<(BB * NN * DD) / 256, 256, 0, stream>>>(vertices, perm_out, out0);
}

// Round 8
// 43.833 us; speedup vs baseline: 29.0417x; 2.3675x over previous
//
#include <hip/hip_runtime.h>
#include <stdint.h>

#define BB 16
#define NN 2048
#define DD 128
#define CC 8

typedef unsigned long long u64;

// ===========================================================================
// k_fused: one block (256 thr) per batch.
// Stage A: bucket sort by (conf desc, idx asc) in LDS:
//   conf^8 ~ uniform -> 2048 buckets ~Poisson(1); histogram + hierarchical
//   prefix + atomic scatter + tiny per-bucket insertion sort (exact keys).
// Stage B: wave 0 = serial greedy (phase 1 demand rows until nbhd==unvis,
//   phase 2 closed-form); waves 1-3 warm first 48 sorted rows into L2.
// ===========================================================================
__global__ __launch_bounds__(256, 1) void k_fused(const float* __restrict__ confid,
                                                  const float* __restrict__ nb,
                                                  float* __restrict__ perm_out) {
    __shared__ u64 keys[NN];              // 16 KB sorted keys (descending)
    __shared__ uint32_t hist[NN];         // 8 KB
    __shared__ uint32_t sOrig[NN];        // 8 KB
    __shared__ uint32_t sInv[NN];         // 8 KB
    __shared__ uint32_t sSing[64];        // 256 B
    __shared__ uint32_t sRs[64];          // 256 B
    __shared__ uint32_t wtot[8];

    int b = blockIdx.x, tid = threadIdx.x;
    int lane = tid & 63, wid = tid >> 6;
    const float* cb = confid + (size_t)b * NN * CC;

    // ---- per-thread: 8 keys + buckets, in registers (static idx only) ----
    u64 key[8]; int bkt[8];
#pragma unroll
    for (int q = 0; q < 8; q++) {
        int i = tid + q * 256;            // element index (order irrelevant)
        const float4* p4 = (const float4*)(cb + (size_t)i * CC);
        float4 a = p4[0], c = p4[1];
        float cf = fmaxf(fmaxf(fmaxf(a.x, a.y), fmaxf(a.z, a.w)),
                         fmaxf(fmaxf(c.x, c.y), fmaxf(c.z, c.w)));
        key[q] = ((u64)__float_as_uint(cf) << 32) | (uint32_t)(NN - 1 - i);
        // bucket: conf^8 ~ uniform; IEEE mul/trunc are monotone -> bucket order
        // respects conf order; exact order fixed by intra-bucket sort below.
        float c2 = cf * cf, c4 = c2 * c2, c8 = c4 * c4;
        int ba = (int)(c8 * 2048.0f);
        ba = ba < 0 ? 0 : (ba > 2047 ? 2047 : ba);
        bkt[q] = 2047 - ba;               // ascending bucket == descending conf
    }
#pragma unroll
    for (int q = 0; q < 8; q++) hist[tid + q * 256] = 0u;
    __syncthreads();
#pragma unroll
    for (int q = 0; q < 8; q++) atomicAdd(&hist[bkt[q]], 1u);
    __syncthreads();

    // ---- exclusive prefix sum of hist: thread-serial + wave shfl + cross-wave ----
    uint32_t v[8], run = 0;
#pragma unroll
    for (int q = 0; q < 8; q++) { v[q] = run; run += hist[tid * 8 + q]; }
    uint32_t inc = run;
#pragma unroll
    for (int s = 1; s < 64; s <<= 1) {
        uint32_t o = (uint32_t)__shfl_up((int)inc, s, 64);
        if (lane >= s) inc += o;
    }
    uint32_t wexc = inc - run;
    if (lane == 63) wtot[wid] = inc;
    __syncthreads();
    uint32_t wbase = 0;
    for (int ww = 0; ww < 4; ww++) if (ww < wid) wbase += wtot[ww];
    uint32_t tbase = wbase + wexc;
#pragma unroll
    for (int q = 0; q < 8; q++) hist[tid * 8 + q] = tbase + v[q];  // own slots only
    __syncthreads();

    // ---- scatter (unstable; fixed by intra-bucket sort) ----
#pragma unroll
    for (int q = 0; q < 8; q++) {
        uint32_t pos = atomicAdd(&hist[bkt[q]], 1u);   // hist becomes bucket END
        keys[pos] = key[q];
    }
    __syncthreads();

    // ---- intra-bucket insertion sort (descending u64 = conf desc, idx asc) ----
    {
        uint32_t segStart = (tid == 0) ? 0u : hist[tid * 8 - 1];
        for (int bq = 0; bq < 8; bq++) {
            uint32_t e = hist[tid * 8 + bq];
            for (uint32_t i = segStart + 1; i < e; i++) {
                u64 kk = keys[i];
                uint32_t j = i;
                while (j > segStart && keys[j - 1] < kk) { keys[j] = keys[j - 1]; j--; }
                keys[j] = kk;
            }
            segStart = e;
        }
    }
    __syncthreads();

    // ---- tables ----
    for (int p = tid; p < NN; p += 256) {
        uint32_t og = (uint32_t)(NN - 1) - (uint32_t)(keys[p] & 0xFFFFFFFFu);
        sOrig[p] = og;
        sInv[og] = (uint32_t)p;
    }
    __syncthreads();
    if (tid < 64) {                       // run flags from neighbor equality
        uint32_t sw = 0, rw = 0;
        for (int k = 0; k < 32; k++) {
            int p = tid * 32 + k;
            uint32_t hc = (uint32_t)(keys[p] >> 32);
            bool isStart = (p == 0) || ((uint32_t)(keys[p - 1] >> 32) != hc);
            bool isEnd = (p == NN - 1) || ((uint32_t)(keys[p + 1] >> 32) != hc);
            rw |= isStart ? (1u << k) : 0u;
            sw |= (isStart && isEnd) ? (1u << k) : 0u;
        }
        sSing[tid] = sw;
        sRs[tid] = rw;
    }
    __syncthreads();

    const float* nbB = nb + (size_t)b * NN * NN;

    // ---- waves 1-3: warm first 48 sorted rows into L2, then exit ----
    if (tid >= 64) {
        int w = tid - 64;                 // 0..191 -> 48 rows x 4 quarters
        int r = w >> 2, quarter = w & 3;
        const float* rowp = nbB + (size_t)sOrig[r] * NN + quarter * 512;
        float acc = 0;
#pragma unroll
        for (int j = 0; j < 32; j++) acc += rowp[j * 16];   // touch every 64B line
        asm volatile("" :: "v"(acc));
        return;
    }

    // ================= Stage B: wave 0 only =================
    float* po = perm_out + b * NN;

    uint32_t ocol[32];                    // my 32 sorted positions' orig indices
#pragma unroll
    for (int k = 0; k < 32; k++) ocol[k] = sOrig[lane * 32 + k];

    uint32_t availW = 0xFFFFFFFFu, nbhdW = 0u, unvisW = 0xFFFFFFFFu;
    uint32_t nonSingW = ~sSing[lane];

    int t = 0;
    // ------------------------- phase 1 -------------------------
    for (; t < NN; t++) {
        uint32_t w = nbhdW & availW;
        u64 m = __ballot(w != 0u);
        int p;
        bool positive;
        if (m) {
            int L = __ffsll(m) - 1;
            uint32_t wl = (uint32_t)__builtin_amdgcn_readlane((int)w, L);
            p = L * 32 + (__ffs(wl) - 1);
            positive = true;
        } else if (__ballot(nbhdW != 0u)) {        // rare: nbhd nonempty, all zeroed
            uint32_t mo = 0xFFFFFFFFu;
#pragma unroll
            for (int k = 0; k < 32; k++)
                if (nbhdW & (1u << k)) mo = min(mo, ocol[k]);
#pragma unroll
            for (int s = 32; s; s >>= 1)
                mo = min(mo, (uint32_t)__shfl_xor((int)mo, s, 64));
            p = (int)sInv[mo];
            positive = false;
        } else {                                   // nbhd empty: global argmax
            u64 ma = __ballot(availW != 0u);
            if (ma) {
                int L = __ffsll(ma) - 1;
                uint32_t wl = (uint32_t)__builtin_amdgcn_readlane((int)availW, L);
                p = L * 32 + (__ffs(wl) - 1);
                positive = true;
            } else {                               // all conf zero -> orig idx 0
                p = (int)sInv[0];
                positive = false;
            }
        }
        p = __builtin_amdgcn_readfirstlane(p);

        uint32_t ogv = sOrig[p];                   // LDS broadcast
        const float* rowp = nbB + (size_t)ogv * NN;
        uint32_t row = 0u;
#pragma unroll
        for (int k = 0; k < 32; k++)
            row |= (rowp[ocol[k]] == 1.0f ? 1u : 0u) << k;

        if (lane == 0) po[t] = (float)ogv;

        uint32_t pbit = (lane == (p >> 5)) ? (1u << (p & 31)) : 0u;
        if (positive) {
            availW &= ~pbit;                       // optimistic singleton clear
            uint32_t nsw = (uint32_t)__builtin_amdgcn_readlane((int)nonSingW, p >> 5);
            if ((nsw >> (p & 31)) & 1u) {          // rare tie-run: walk run extent
                uint32_t hc = (uint32_t)(keys[p] >> 32);
                int rs = p, re = p;
                while (rs > 0 && (uint32_t)(keys[rs - 1] >> 32) == hc) rs--;
                while (re < NN - 1 && (uint32_t)(keys[re + 1] >> 32) == hc) re++;
                int lo = rs - lane * 32;     lo = lo < 0 ? 0 : (lo > 32 ? 32 : lo);
                int hi = re + 1 - lane * 32; hi = hi < 0 ? 0 : (hi > 32 ? 32 : hi);
                if (hi > lo) {
                    uint32_t mh = (hi >= 32) ? 0xFFFFFFFFu : ((1u << hi) - 1u);
                    uint32_t ml = (1u << lo) - 1u;
                    availW &= ~(mh & ~ml);
                }
            }
        }
        nbhdW  = (nbhdW & ~pbit) | (row & unvisW);
        unvisW &= ~pbit;

        uint32_t nnb = unvisW & ~nbhdW;            // unreached & unvisited
        if (__ballot(nnb != 0u) == 0ULL) { t++; break; }  // nbhd==unvis forever
    }

    // ------------------------- phase 2 -------------------------
    if (t < NN) {
        uint32_t liveW = availW & unvisW;
        uint32_t rsW = sRs[lane];
        uint32_t pm = liveW & rsW;                 // fast-pick set (run reps)
        int cnt = __popc(pm);
        int inc2 = cnt;
#pragma unroll
        for (int s = 1; s < 64; s <<= 1) {
            int o = __shfl_up(inc2, s, 64);
            if (lane >= s) inc2 += o;
        }
        int pre = inc2 - cnt;                      // exclusive prefix
        int T2 = __shfl(inc2, 63, 64);             // total fast picks

        int tt = t + pre;
#pragma unroll
        for (int k = 0; k < 32; k++) {
            if (pm & (1u << k)) { po[tt] = (float)ocol[k]; tt++; }
        }
        t += T2;

        // leftovers: unvisited non-reps (zero-conf tie losers), ascending orig
        uint32_t lm = unvisW & ~pm;
        while (__ballot(lm != 0u)) {
            uint32_t mo = 0xFFFFFFFFu;
#pragma unroll
            for (int k = 0; k < 32; k++)
                if (lm & (1u << k)) mo = min(mo, ocol[k]);
#pragma unroll
            for (int s = 32; s; s >>= 1)
                mo = min(mo, (uint32_t)__shfl_xor((int)mo, s, 64));
            if (lane == 0) po[t] = (float)mo;
            t++;
#pragma unroll
            for (int k = 0; k < 32; k++)
                if ((lm & (1u << k)) && ocol[k] == mo) lm &= ~(1u << k);
        }
    }
}

// ===========================================================================
// k_gather: out0[b,t,:] = vertices[b, perm[t], :]
// ===========================================================================
__global__ __launch_bounds__(256) void k_gather(const float* __restrict__ vtx,
                                                const float* __restrict__ perm_f,
                                                float* __restrict__ out0) {
    int tid = blockIdx.x * 256 + threadIdx.x;
    int d = tid & (DD - 1);
    int t = (tid >> 7) & (NN - 1);
    int b = tid >> 18;
    int p = (int)perm_f[b * NN + t];
    out0[tid] = vtx[(((size_t)b * NN + p) << 7) + d];
}

// ===========================================================================
extern "C" void kernel_launch(void* const* d_in, const int* in_sizes, int n_in,
                              void* d_out, int out_size, void* d_ws, size_t ws_size,
                              hipStream_t stream) {
    const float* vertices   = (const float*)d_in[0];
    const float* confidence = (const float*)d_in[1];
    const float* neighbors  = (const float*)d_in[2];

    float* out0     = (float*)d_out;                   // [B,N,D]
    float* perm_out = out0 + (size_t)BB * NN * DD;     // [B,N] as f32 values

    k_fused<<<BB, 256, 0, stream>>>(confidence, neighbors, perm_out);
    k_gather<<<(BB * NN * DD) / 256, 256, 0, stream>>>(vertices, perm_out, out0);
}

// Round 9
// 39.920 us; speedup vs baseline: 31.8884x; 1.0980x over previous
//
#include <hip/hip_runtime.h>
#include <stdint.h>

#define BB 16
#define NN 2048
#define DD 128
#define CC 8

typedef unsigned long long u64;

// ===========================================================================
// k_fused: one block (256 thr) per batch.
// Stage A: bucket sort by (conf desc, idx asc) in LDS (conf^8 ~ uniform ->
//   2048 buckets; histogram + hierarchical prefix + atomic scatter + tiny
//   per-bucket insertion sort on exact keys).
// Stage B: wave 0 = serial greedy; waves 1-3 warm first 48 sorted rows into
//   L2, then exit. Phase-1 rows: COALESCED float4 load -> LDS stage ->
//   scattered LDS reads for the sorted-domain permutation (replaces the
//   2000-cycle scattered-global gather). Phase 2 closed-form.
// ===========================================================================
__global__ __launch_bounds__(256, 1) void k_fused(const float* __restrict__ confid,
                                                  const float* __restrict__ nb,
                                                  float* __restrict__ perm_out) {
    __shared__ u64 keys[NN];              // 16 KB sorted keys (descending)
    __shared__ uint32_t hist[NN];         // 8 KB
    __shared__ uint32_t sOrig[NN];        // 8 KB
    __shared__ uint32_t sInv[NN];         // 8 KB
    __shared__ float4 sRowV[NN / 4];      // 8 KB row staging (phase 1)
    __shared__ uint32_t sSing[64];        // 256 B
    __shared__ uint32_t sRs[64];          // 256 B
    __shared__ uint32_t wtot[8];

    int b = blockIdx.x, tid = threadIdx.x;
    int lane = tid & 63, wid = tid >> 6;
    const float* cb = confid + (size_t)b * NN * CC;

    // ---- per-thread: 8 keys + buckets, in registers (static idx only) ----
    u64 key[8]; int bkt[8];
#pragma unroll
    for (int q = 0; q < 8; q++) {
        int i = tid + q * 256;            // element index (order irrelevant)
        const float4* p4 = (const float4*)(cb + (size_t)i * CC);
        float4 a = p4[0], c = p4[1];
        float cf = fmaxf(fmaxf(fmaxf(a.x, a.y), fmaxf(a.z, a.w)),
                         fmaxf(fmaxf(c.x, c.y), fmaxf(c.z, c.w)));
        key[q] = ((u64)__float_as_uint(cf) << 32) | (uint32_t)(NN - 1 - i);
        // bucket: conf^8 ~ uniform; IEEE mul/trunc monotone -> bucket order
        // respects conf order; exact order fixed by intra-bucket sort below.
        float c2 = cf * cf, c4 = c2 * c2, c8 = c4 * c4;
        int ba = (int)(c8 * 2048.0f);
        ba = ba < 0 ? 0 : (ba > 2047 ? 2047 : ba);
        bkt[q] = 2047 - ba;               // ascending bucket == descending conf
    }
#pragma unroll
    for (int q = 0; q < 8; q++) hist[tid + q * 256] = 0u;
    __syncthreads();
#pragma unroll
    for (int q = 0; q < 8; q++) atomicAdd(&hist[bkt[q]], 1u);
    __syncthreads();

    // ---- exclusive prefix sum of hist: thread-serial + wave shfl + cross-wave ----
    uint32_t v[8], run = 0;
#pragma unroll
    for (int q = 0; q < 8; q++) { v[q] = run; run += hist[tid * 8 + q]; }
    uint32_t inc = run;
#pragma unroll
    for (int s = 1; s < 64; s <<= 1) {
        uint32_t o = (uint32_t)__shfl_up((int)inc, s, 64);
        if (lane >= s) inc += o;
    }
    uint32_t wexc = inc - run;
    if (lane == 63) wtot[wid] = inc;
    __syncthreads();
    uint32_t wbase = 0;
    for (int ww = 0; ww < 4; ww++) if (ww < wid) wbase += wtot[ww];
    uint32_t tbase = wbase + wexc;
#pragma unroll
    for (int q = 0; q < 8; q++) hist[tid * 8 + q] = tbase + v[q];  // own slots only
    __syncthreads();

    // ---- scatter (unstable; fixed by intra-bucket sort) ----
#pragma unroll
    for (int q = 0; q < 8; q++) {
        uint32_t pos = atomicAdd(&hist[bkt[q]], 1u);   // hist becomes bucket END
        keys[pos] = key[q];
    }
    __syncthreads();

    // ---- intra-bucket insertion sort (descending u64 = conf desc, idx asc) ----
    {
        uint32_t segStart = (tid == 0) ? 0u : hist[tid * 8 - 1];
        for (int bq = 0; bq < 8; bq++) {
            uint32_t e = hist[tid * 8 + bq];
            for (uint32_t i = segStart + 1; i < e; i++) {
                u64 kk = keys[i];
                uint32_t j = i;
                while (j > segStart && keys[j - 1] < kk) { keys[j] = keys[j - 1]; j--; }
                keys[j] = kk;
            }
            segStart = e;
        }
    }
    __syncthreads();

    // ---- tables ----
    for (int p = tid; p < NN; p += 256) {
        uint32_t og = (uint32_t)(NN - 1) - (uint32_t)(keys[p] & 0xFFFFFFFFu);
        sOrig[p] = og;
        sInv[og] = (uint32_t)p;
    }
    __syncthreads();
    if (tid < 64) {                       // run flags from neighbor equality
        uint32_t sw = 0, rw = 0;
        for (int k = 0; k < 32; k++) {
            int p = tid * 32 + k;
            uint32_t hc = (uint32_t)(keys[p] >> 32);
            bool isStart = (p == 0) || ((uint32_t)(keys[p - 1] >> 32) != hc);
            bool isEnd = (p == NN - 1) || ((uint32_t)(keys[p + 1] >> 32) != hc);
            rw |= isStart ? (1u << k) : 0u;
            sw |= (isStart && isEnd) ? (1u << k) : 0u;
        }
        sSing[tid] = sw;
        sRs[tid] = rw;
    }
    __syncthreads();

    const float* nbB = nb + (size_t)b * NN * NN;

    // ---- waves 1-3: warm first 48 sorted rows into L2, then exit ----
    if (tid >= 64) {
        int w = tid - 64;                 // 0..191 -> 48 rows x 4 quarters
        int r = w >> 2, quarter = w & 3;
        const float* rowp = nbB + (size_t)sOrig[r] * NN + quarter * 512;
        float acc = 0;
#pragma unroll
        for (int j = 0; j < 32; j++) acc += rowp[j * 16];   // touch every 64B line
        asm volatile("" :: "v"(acc));
        return;
    }

    // ================= Stage B: wave 0 only =================
    float* po = perm_out + b * NN;
    float* sRowF = (float*)sRowV;

    uint32_t ocol[32];                    // my 32 sorted positions' orig indices
#pragma unroll
    for (int k = 0; k < 32; k++) ocol[k] = sOrig[lane * 32 + k];

    uint32_t availW = 0xFFFFFFFFu, nbhdW = 0u, unvisW = 0xFFFFFFFFu;
    uint32_t nonSingW = ~sSing[lane];

    int t = 0;
    // ------------------------- phase 1 -------------------------
    for (; t < NN; t++) {
        uint32_t w = nbhdW & availW;
        u64 m = __ballot(w != 0u);
        int p;
        bool positive;
        if (m) {
            int L = __ffsll(m) - 1;
            uint32_t wl = (uint32_t)__builtin_amdgcn_readlane((int)w, L);
            p = L * 32 + (__ffs(wl) - 1);
            positive = true;
        } else if (__ballot(nbhdW != 0u)) {        // rare: nbhd nonempty, all zeroed
            uint32_t mo = 0xFFFFFFFFu;
#pragma unroll
            for (int k = 0; k < 32; k++)
                if (nbhdW & (1u << k)) mo = min(mo, ocol[k]);
#pragma unroll
            for (int s = 32; s; s >>= 1)
                mo = min(mo, (uint32_t)__shfl_xor((int)mo, s, 64));
            p = (int)sInv[mo];
            positive = false;
        } else {                                   // nbhd empty: global argmax
            u64 ma = __ballot(availW != 0u);
            if (ma) {
                int L = __ffsll(ma) - 1;
                uint32_t wl = (uint32_t)__builtin_amdgcn_readlane((int)availW, L);
                p = L * 32 + (__ffs(wl) - 1);
                positive = true;
            } else {                               // all conf zero -> orig idx 0
                p = (int)sInv[0];
                positive = false;
            }
        }
        p = __builtin_amdgcn_readfirstlane(p);

        uint32_t ogv = sOrig[p];                   // LDS broadcast
        // ---- coalesced row load -> LDS stage (replaces scattered global) ----
        const float4* rv = (const float4*)(nbB + (size_t)ogv * NN);
#pragma unroll
        for (int c = 0; c < 8; c++)
            sRowV[c * 64 + lane] = rv[c * 64 + lane];   // 1KB coalesced each
        // wave-internal RAW on LDS: compiler inserts lgkmcnt waits.
        uint32_t row = 0u;
#pragma unroll
        for (int k = 0; k < 32; k++)
            row |= (sRowF[ocol[k]] == 1.0f ? 1u : 0u) << k;

        if (lane == 0) po[t] = (float)ogv;

        uint32_t pbit = (lane == (p >> 5)) ? (1u << (p & 31)) : 0u;
        if (positive) {
            availW &= ~pbit;                       // optimistic singleton clear
            uint32_t nsw = (uint32_t)__builtin_amdgcn_readlane((int)nonSingW, p >> 5);
            if ((nsw >> (p & 31)) & 1u) {          // rare tie-run: walk run extent
                uint32_t hc = (uint32_t)(keys[p] >> 32);
                int rs = p, re = p;
                while (rs > 0 && (uint32_t)(keys[rs - 1] >> 32) == hc) rs--;
                while (re < NN - 1 && (uint32_t)(keys[re + 1] >> 32) == hc) re++;
                int lo = rs - lane * 32;     lo = lo < 0 ? 0 : (lo > 32 ? 32 : lo);
                int hi = re + 1 - lane * 32; hi = hi < 0 ? 0 : (hi > 32 ? 32 : hi);
                if (hi > lo) {
                    uint32_t mh = (hi >= 32) ? 0xFFFFFFFFu : ((1u << hi) - 1u);
                    uint32_t ml = (1u << lo) - 1u;
                    availW &= ~(mh & ~ml);
                }
            }
        }
        nbhdW  = (nbhdW & ~pbit) | (row & unvisW);
        unvisW &= ~pbit;

        uint32_t nnb = unvisW & ~nbhdW;            // unreached & unvisited
        if (__ballot(nnb != 0u) == 0ULL) { t++; break; }  // nbhd==unvis forever
    }

    // ------------------------- phase 2 -------------------------
    if (t < NN) {
        uint32_t liveW = availW & unvisW;
        uint32_t rsW = sRs[lane];
        uint32_t pm = liveW & rsW;                 // fast-pick set (run reps)
        int cnt = __popc(pm);
        int inc2 = cnt;
#pragma unroll
        for (int s = 1; s < 64; s <<= 1) {
            int o = __shfl_up(inc2, s, 64);
            if (lane >= s) inc2 += o;
        }
        int pre = inc2 - cnt;                      // exclusive prefix
        int T2 = __shfl(inc2, 63, 64);             // total fast picks

        int tt = t + pre;
#pragma unroll
        for (int k = 0; k < 32; k++) {
            if (pm & (1u << k)) { po[tt] = (float)ocol[k]; tt++; }
        }
        t += T2;

        // leftovers: unvisited non-reps (zero-conf tie losers), ascending orig
        uint32_t lm = unvisW & ~pm;
        while (__ballot(lm != 0u)) {
            uint32_t mo = 0xFFFFFFFFu;
#pragma unroll
            for (int k = 0; k < 32; k++)
                if (lm & (1u << k)) mo = min(mo, ocol[k]);
#pragma unroll
            for (int s = 32; s; s >>= 1)
                mo = min(mo, (uint32_t)__shfl_xor((int)mo, s, 64));
            if (lane == 0) po[t] = (float)mo;
            t++;
#pragma unroll
            for (int k = 0; k < 32; k++)
                if ((lm & (1u << k)) && ocol[k] == mo) lm &= ~(1u << k);
        }
    }
}

// ===========================================================================
// k_gather (float4): out0[b,t,:] = vertices[b, perm[t], :]
// ===========================================================================
__global__ __launch_bounds__(256) void k_gather(const float* __restrict__ vtx,
                                                const float* __restrict__ perm_f,
                                                float* __restrict__ out0) {
    int tid = blockIdx.x * 256 + threadIdx.x;      // [0, BB*NN*DD/4)
    int d4 = tid & (DD / 4 - 1);                   // float4 index in row
    int t  = (tid >> 5) & (NN - 1);
    int b  = tid >> 16;
    int p = (int)perm_f[b * NN + t];
    const float4* v4 = (const float4*)vtx;
    ((float4*)out0)[tid] = v4[(((size_t)b * NN + p) << 5) + d4];
}

// ===========================================================================
extern "C" void kernel_launch(void* const* d_in, const int* in_sizes, int n_in,
                              void* d_out, int out_size, void* d_ws, size_t ws_size,
                              hipStream_t stream) {
    const float* vertices   = (const float*)d_in[0];
    const float* confidence = (const float*)d_in[1];
    const float* neighbors  = (const float*)d_in[2];

    float* out0     = (float*)d_out;                   // [B,N,D]
    float* perm_out = out0 + (size_t)BB * NN * DD;     // [B,N] as f32 values

    k_fused<<<BB, 256, 0, stream>>>(confidence, neighbors, perm_out);
    k_gather<<<(BB * NN * DD / 4) / 256, 256, 0, stream>>>(vertices, perm_out, out0);
}